// Round 13
// baseline (261.575 us; speedup 1.0000x reference)
//
#include <hip/hip_runtime.h>

// ---------- constants for this problem ----------
#define BATCH 2
#define NTOK 2048          // image tokens per batch
#define MTOK 256           // text tokens per batch
#define CDIM 1024
#define NHEAD 16
#define HD 64
#define SEQ (NTOK + MTOK)  // 2304
#define TOK_X (BATCH * NTOK)   // 4096
#define TOK_Y (BATCH * MTOK)   // 512
#define BHN (BATCH * NHEAD)    // 32
#define NKT (SEQ / 64)         // 36 KV tiles
#define HALFKEYS (SEQ / 2)     // 1152
#define NKTH (NKT / 2)         // 18 tiles per half

typedef __attribute__((ext_vector_type(8))) short bf16x8;
typedef __attribute__((ext_vector_type(4))) short bf16x4;
typedef __attribute__((ext_vector_type(4))) float f32x4;
typedef __attribute__((ext_vector_type(2))) unsigned int u32x2;
typedef __attribute__((ext_vector_type(4))) unsigned int u32x4;
#if __has_builtin(__builtin_amdgcn_cvt_pk_bf16_f32)
typedef __attribute__((ext_vector_type(2))) __bf16 bf16x2_t;
#endif

__device__ __forceinline__ float b2f(ushort u) {
    unsigned v = ((unsigned)u) << 16;
    return __builtin_bit_cast(float, v);
}
__device__ __forceinline__ ushort f2b(float f) {
    unsigned u = __builtin_bit_cast(unsigned, f);
    u += 0x7fffu + ((u >> 16) & 1u);   // round-to-nearest-even
    return (ushort)(u >> 16);
}
__device__ __forceinline__ unsigned pack2bf(float a, float b) {
#if __has_builtin(__builtin_amdgcn_cvt_pk_bf16_f32)
    bf16x2_t h = __builtin_amdgcn_cvt_pk_bf16_f32(a, b);   // lo=a, hi=b
    return __builtin_bit_cast(unsigned, h);
#else
    return ((unsigned)f2b(b) << 16) | (unsigned)f2b(a);
#endif
}

// async 16B global -> LDS; LDS dest = wave-uniform base, HW scatters lane*16B
__device__ __forceinline__ void async_load16(const ushort* g, ushort* l) {
    __builtin_amdgcn_global_load_lds(
        (const __attribute__((address_space(1))) unsigned*)(const void*)g,
        (__attribute__((address_space(3))) unsigned*)(void*)l, 16, 0, 0);
}

// ---------- one merged cast kernel: 5 fp32->bf16 segments ----------
__global__ __launch_bounds__(256) void cast_all(
    const float* __restrict__ s0, ushort* __restrict__ t0, int b0,
    const float* __restrict__ s1, ushort* __restrict__ t1, int b1,
    const float* __restrict__ s2, ushort* __restrict__ t2, int b2,
    const float* __restrict__ s3, ushort* __restrict__ t3, int b3,
    const float* __restrict__ s4, ushort* __restrict__ t4) {
    int blk = blockIdx.x;
    const float* s; ushort* t;
    if (blk < b0)      { s = s0; t = t0; }
    else if (blk < b1) { s = s1; t = t1; blk -= b0; }
    else if (blk < b2) { s = s2; t = t2; blk -= b1; }
    else if (blk < b3) { s = s3; t = t3; blk -= b2; }
    else               { s = s4; t = t4; blk -= b3; }
    int i = (blk * 256 + threadIdx.x) * 8;
    float4 a = *(const float4*)(s + i);
    float4 b = *(const float4*)(s + i + 4);
    ushort tmp[8] = {f2b(a.x), f2b(a.y), f2b(a.z), f2b(a.w),
                     f2b(b.x), f2b(b.y), f2b(b.z), f2b(b.w)};
    *(uint4*)(t + i) = *(const uint4*)tmp;
}

// ---------- fused GEMM: C = A * Bt^T + bias, with per-mode epilogue (R8) ----------
template <int MODE>
__global__ __launch_bounds__(256) void gemm_fused(const ushort* __restrict__ A,
                                                  const ushort* __restrict__ Bt,
                                                  const float* __restrict__ bias,
                                                  float* __restrict__ Cf,
                                                  ushort* __restrict__ d_q,
                                                  ushort* __restrict__ d_k,
                                                  ushort* __restrict__ d_v,
                                                  const float* __restrict__ qn_w,
                                                  const float* __restrict__ kn_w,
                                                  int M, int N, int K) {
    __shared__ ushort As[128][64];
    __shared__ ushort Bs[128][64];
    int tid = threadIdx.x;
    int lane = tid & 63;
    int w = tid >> 6;
    int wm = (w >> 1) * 64;
    int wn = (w & 1) * 64;
    int l15 = lane & 15;
    int quad = lane >> 4;
    int sw = l15 & 7;
    int bm = blockIdx.y * 128;
    int bn = blockIdx.x * 128;

    f32x4 acc[4][4];
#pragma unroll
    for (int i = 0; i < 4; i++)
#pragma unroll
        for (int j = 0; j < 4; j++) acc[i][j] = (f32x4)0.0f;

    int lrow = lane >> 3;
    int lcol = ((lane & 7) ^ lrow) * 8;

    for (int k0 = 0; k0 < K; k0 += 64) {
        __syncthreads();
#pragma unroll
        for (int p = 0; p < 4; p++) {
            int rb = w * 32 + p * 8;
            async_load16(&A[(size_t)(bm + rb + lrow) * K + k0 + lcol], &As[rb][0]);
            async_load16(&Bt[(size_t)(bn + rb + lrow) * K + k0 + lcol], &Bs[rb][0]);
        }
        __syncthreads();
#pragma unroll
        for (int kk = 0; kk < 64; kk += 32) {
            bf16x8 af[4], bfr[4];
            int g = (kk >> 3) + quad;
            int csw = (g ^ sw) * 8;
#pragma unroll
            for (int i = 0; i < 4; i++)
                af[i] = *(const bf16x8*)&As[wm + i * 16 + l15][csw];
#pragma unroll
            for (int j = 0; j < 4; j++)
                bfr[j] = *(const bf16x8*)&Bs[wn + j * 16 + l15][csw];
#pragma unroll
            for (int i = 0; i < 4; i++)
#pragma unroll
                for (int j = 0; j < 4; j++)
                    acc[i][j] = __builtin_amdgcn_mfma_f32_16x16x32_bf16(af[i], bfr[j], acc[i][j], 0, 0, 0);
        }
    }

    int colbase = bn + wn;   // 64-aligned; one head's d-range
    float bv[4];
#pragma unroll
    for (int j = 0; j < 4; j++) bv[j] = bias[colbase + j * 16 + l15];
#pragma unroll
    for (int i = 0; i < 4; i++)
#pragma unroll
        for (int j = 0; j < 4; j++)
#pragma unroll
            for (int r = 0; r < 4; r++) acc[i][j][r] += bv[j];

    if (MODE == 0) {
#pragma unroll
        for (int i = 0; i < 4; i++) {
            int row0 = bm + wm + i * 16 + quad * 4;
#pragma unroll
            for (int j = 0; j < 4; j++) {
                int col = colbase + j * 16 + l15;
#pragma unroll
                for (int r = 0; r < 4; r++)
                    Cf[(size_t)(row0 + r) * N + col] = acc[i][j][r];
            }
        }
        return;
    }

    // MODE 1 (qkv): region 0=q,1=k,2=v ; MODE 2 (kv): region 0=k,1=v
    int region = colbase >> 10;
    int h = (colbase >> 6) & (NHEAD - 1);
    bool do_norm = (MODE == 1) ? (region <= 1) : (region == 0);
    if (do_norm) {
        const float* wv = (MODE == 1 && region == 0) ? qn_w : kn_w;
        float wj[4];
#pragma unroll
        for (int j = 0; j < 4; j++) wj[j] = wv[j * 16 + l15];
        float qs = (MODE == 1 && region == 0) ? (0.125f * 1.44269504088896f) : 1.0f;
#pragma unroll
        for (int i = 0; i < 4; i++)
#pragma unroll
            for (int r = 0; r < 4; r++) {
                float s = acc[i][0][r] * acc[i][0][r] + acc[i][1][r] * acc[i][1][r]
                        + acc[i][2][r] * acc[i][2][r] + acc[i][3][r] * acc[i][3][r];
                s += __shfl_xor(s, 1);
                s += __shfl_xor(s, 2);
                s += __shfl_xor(s, 4);
                s += __shfl_xor(s, 8);
                float rs = rsqrtf(s * (1.0f / 64.0f) + 1e-6f) * qs;
#pragma unroll
                for (int j = 0; j < 4; j++) acc[i][j][r] *= rs * wj[j];
            }
    }
#pragma unroll
    for (int i = 0; i < 4; i++) {
#pragma unroll
        for (int r = 0; r < 4; r++) {
            int t = bm + wm + i * 16 + quad * 4 + r;   // token row
            size_t base;
            ushort* dst;
            if (MODE == 1) {
                int b = t >> 11, n = t & (NTOK - 1);
                size_t bh = (size_t)(b * NHEAD + h);
                if (region == 0)      { dst = d_q; base = (bh * NTOK + n) * 64; }
                else if (region == 1) { dst = d_k; base = (bh * SEQ + n) * 64; }
                else                  { dst = d_v; base = (bh * SEQ + n) * 64; }
            } else {
                int b = t >> 8, m = t & (MTOK - 1);
                size_t bh = (size_t)(b * NHEAD + h);
                if (region == 0) { dst = d_k; base = (bh * SEQ + NTOK + m) * 64; }
                else             { dst = d_v; base = (bh * SEQ + NTOK + m) * 64; }
            }
#pragma unroll
            for (int j = 0; j < 4; j++)
                dst[base + j * 16 + l15] = f2b(acc[i][j][r]);
        }
    }
}

// ---------- transpose V: vc [BHN][SEQ][64] -> vt [BHN][64][SEQ] (k-PAIR-INTERLEAVED) ----------
__global__ __launch_bounds__(256) void transpose_v(const ushort* __restrict__ vc,
                                                   ushort* __restrict__ vt) {
    __shared__ ushort t[64][72];
    int bh = blockIdx.y;
    int s0 = blockIdx.x * 64;
    int tid = threadIdx.x;
    int r = tid >> 3, c = (tid & 7) * 8;
    const ushort* src = vc + ((size_t)bh * SEQ + s0) * 64;
    *(uint4*)&t[r][c] = *(const uint4*)&src[(size_t)r * 64 + c];
    *(uint4*)&t[r + 32][c] = *(const uint4*)&src[(size_t)(r + 32) * 64 + c];
    __syncthreads();
    ushort* dst = vt + (size_t)bh * 64 * SEQ + s0;
#pragma unroll
    for (int p = 0; p < 2; p++) {
        int d = (tid >> 3) + p * 32;
        int s8 = (tid & 7) * 8;
        ushort tmp[8];
#pragma unroll
        for (int i = 0; i < 8; i++) {
            int cc = s8 + i;                                // dst position
            int srcs = (cc & 32) + ((cc & 31) >> 1) + ((cc & 1) << 4);  // source key
            tmp[i] = t[srcs][d];
        }
        *(uint4*)&dst[(size_t)d * SEQ + s8] = *(const uint4*)tmp;
    }
}

// ---------- flash attention, KV-SPLIT: grid (NTOK/128, BHN*2) ----------
// R13: fixed-point softmax (no max) makes unnormalized O and l ADDITIVE over
// keys, so each block handles half the KV range (18 tiles) and writes bf16
// partial O + fp32 partial l. Grid 512 -> 1024 = 4 blocks/CU (was 2): double
// the waves to hide the ds_read->QK->exp2->PV serial chain. Combine kernel
// normalizes. Structure otherwise identical to R12 (x32 PV, 64-key dbuf).
__global__ __launch_bounds__(256) void attn_fwd(const ushort* __restrict__ qh,
                                                const ushort* __restrict__ kc,
                                                const ushort* __restrict__ vt,
                                                ushort* __restrict__ po,
                                                float* __restrict__ pl) {
    __shared__ ushort Ks[2][64][72];   // [buf][key][d]
    __shared__ ushort Vs[2][64][68];   // [buf][d][key-interleaved]
    int tid = threadIdx.x;
    int lane = tid & 63;
    int w = tid >> 6;
    int l15 = lane & 15;
    int quad = lane >> 4;
    int bhh = blockIdx.y;
    int half = bhh & 1;
    int bh = bhh >> 1;
    int q0 = blockIdx.x * 128 + w * 32;

    const ushort* qpA = qh + ((size_t)bh * NTOK + q0 + l15) * 64 + quad * 8;
    const ushort* qpB = qpA + 16 * 64;
    bf16x8 qA0 = *(const bf16x8*)qpA;
    bf16x8 qA1 = *(const bf16x8*)(qpA + 32);
    bf16x8 qB0 = *(const bf16x8*)qpB;
    bf16x8 qB1 = *(const bf16x8*)(qpB + 32);

    float lA = 0.0f, lB = 0.0f;
    f32x4 OA[4], OB[4];
#pragma unroll
    for (int jd = 0; jd < 4; jd++) { OA[jd] = (f32x4)0.0f; OB[jd] = (f32x4)0.0f; }

    const ushort* kbase = kc + ((size_t)bh * SEQ + half * HALFKEYS) * 64;
    const ushort* vbase = vt + (size_t)bh * 64 * SEQ + half * HALFKEYS;
    int sr = tid >> 3, sc = (tid & 7) * 8;
    const ushort* kp0 = kbase + (size_t)sr * 64 + sc;
    const ushort* kp1 = kbase + (size_t)(sr + 32) * 64 + sc;
    const ushort* vp0 = vbase + (size_t)sr * SEQ + sc;
    const ushort* vp1 = vbase + (size_t)(sr + 32) * SEQ + sc;

    // prefetch tile 0 into registers
    uint4 rka = *(const uint4*)kp0;
    uint4 rkb = *(const uint4*)kp1;
    uint4 rva = *(const uint4*)vp0;
    uint4 rvb = *(const uint4*)vp1;

    for (int t = 0; t < NKTH; t++) {
        int p = t & 1;
        *(uint4*)&Ks[p][sr][sc] = rka;
        *(uint4*)&Ks[p][sr + 32][sc] = rkb;
        *(uint4*)&Vs[p][sr][sc] = rva;
        *(uint4*)&Vs[p][sr + 32][sc] = rvb;
        __syncthreads();
        if (t + 1 < NKTH) {
            int s0 = (t + 1) * 64;
            rka = *(const uint4*)(kp0 + (size_t)s0 * 64);
            rkb = *(const uint4*)(kp1 + (size_t)s0 * 64);
            rva = *(const uint4*)(vp0 + s0);
            rvb = *(const uint4*)(vp1 + s0);
        }

        f32x4 SA[4], SB[4];
#pragma unroll
        for (int j = 0; j < 4; j++) { SA[j] = (f32x4)0.0f; SB[j] = (f32x4)0.0f; }
#pragma unroll
        for (int j = 0; j < 4; j++) {
            bf16x8 kf = *(const bf16x8*)&Ks[p][j * 16 + l15][quad * 8];
            SA[j] = __builtin_amdgcn_mfma_f32_16x16x32_bf16(kf, qA0, SA[j], 0, 0, 0);
            SB[j] = __builtin_amdgcn_mfma_f32_16x16x32_bf16(kf, qB0, SB[j], 0, 0, 0);
        }
#pragma unroll
        for (int j = 0; j < 4; j++) {
            bf16x8 kf = *(const bf16x8*)&Ks[p][j * 16 + l15][32 + quad * 8];
            SA[j] = __builtin_amdgcn_mfma_f32_16x16x32_bf16(kf, qA1, SA[j], 0, 0, 0);
            SB[j] = __builtin_amdgcn_mfma_f32_16x16x32_bf16(kf, qB1, SB[j], 0, 0, 0);
        }

#pragma unroll
        for (int pb2 = 0; pb2 < 2; pb2++) {
            int j0 = 2 * pb2, j1 = j0 + 1;
            u32x4 wa, wb;
#pragma unroll
            for (int r = 0; r < 4; r++) {
                float a0 = __builtin_amdgcn_exp2f(SA[j0][r]);
                float a1 = __builtin_amdgcn_exp2f(SA[j1][r]);
                lA += a0 + a1;
                wa[r] = pack2bf(a0, a1);
                float b0 = __builtin_amdgcn_exp2f(SB[j0][r]);
                float b1 = __builtin_amdgcn_exp2f(SB[j1][r]);
                lB += b0 + b1;
                wb[r] = pack2bf(b0, b1);
            }
            bf16x8 pA = __builtin_bit_cast(bf16x8, wa);
            bf16x8 pB = __builtin_bit_cast(bf16x8, wb);
#pragma unroll
            for (int jd = 0; jd < 4; jd++) {
                bf16x8 vf = *(const bf16x8*)&Vs[p][jd * 16 + l15][pb2 * 32 + quad * 8];
                OA[jd] = __builtin_amdgcn_mfma_f32_16x16x32_bf16(vf, pA, OA[jd], 0, 0, 0);
                OB[jd] = __builtin_amdgcn_mfma_f32_16x16x32_bf16(vf, pB, OB[jd], 0, 0, 0);
            }
        }
    }
    // epilogue: store UNNORMALIZED partial O (bf16) + partial l (fp32)
    lA += __shfl_xor(lA, 16);
    lA += __shfl_xor(lA, 32);
    lB += __shfl_xor(lB, 16);
    lB += __shfl_xor(lB, 32);
    int b = bh >> 4, h = bh & 15;
    int tokA = (b << 11) + q0 + l15;
    ushort* obaseA = po + (size_t)half * TOK_X * CDIM + ((size_t)tokA * NHEAD + h) * 64;
    ushort* obaseB = obaseA + (size_t)16 * NHEAD * 64;
#pragma unroll
    for (int jd = 0; jd < 4; jd++) {
        u32x2 pk;
        pk.x = pack2bf(OA[jd][0], OA[jd][1]);
        pk.y = pack2bf(OA[jd][2], OA[jd][3]);
        *(u32x2*)&obaseA[jd * 16 + quad * 4] = pk;
        pk.x = pack2bf(OB[jd][0], OB[jd][1]);
        pk.y = pack2bf(OB[jd][2], OB[jd][3]);
        *(u32x2*)&obaseB[jd * 16 + quad * 4] = pk;
    }
    if (lane < 16) {   // quad 0 holds the full sums
        float* plh = pl + (size_t)(half * BHN + bh) * NTOK;
        plh[q0 + l15] = lA;
        plh[q0 + 16 + l15] = lB;
    }
}

// ---------- combine: ao = (po[0] + po[1]) / (l0 + l1), bf16 out ----------
__global__ __launch_bounds__(256) void combine_halves(const ushort* __restrict__ po,
                                                      const float* __restrict__ pl,
                                                      ushort* __restrict__ ao) {
    int idx = (blockIdx.x * 256 + threadIdx.x) * 8;   // over TOK_X*CDIM
    int tok = idx >> 10;
    int c = idx & (CDIM - 1);
    int h = c >> 6;
    int b = tok >> 11, n = tok & (NTOK - 1);
    int bh = b * NHEAD + h;
    float l = pl[(size_t)bh * NTOK + n] + pl[(size_t)(BHN + bh) * NTOK + n];
    float inv = 1.0f / l;
    uint4 a0 = *(const uint4*)&po[idx];
    uint4 a1 = *(const uint4*)&po[(size_t)TOK_X * CDIM + idx];
    const ushort* u0 = (const ushort*)&a0;
    const ushort* u1 = (const ushort*)&a1;
    unsigned outw[4];
#pragma unroll
    for (int i = 0; i < 4; i++) {
        float e0 = (b2f(u0[2 * i]) + b2f(u1[2 * i])) * inv;
        float e1 = (b2f(u0[2 * i + 1]) + b2f(u1[2 * i + 1])) * inv;
        outw[i] = pack2bf(e0, e1);
    }
    *(uint4*)&ao[idx] = *(const uint4*)outw;
}

// ---------- launch ----------
extern "C" void kernel_launch(void* const* d_in, const int* in_sizes, int n_in,
                              void* d_out, int out_size, void* d_ws, size_t ws_size,
                              hipStream_t stream) {
    const float* x      = (const float*)d_in[0];
    const float* y      = (const float*)d_in[1];
    const float* qkv_w  = (const float*)d_in[2];
    const float* qkv_b  = (const float*)d_in[3];
    const float* kv_w   = (const float*)d_in[4];
    const float* kv_b   = (const float*)d_in[5];
    const float* qn_w   = (const float*)d_in[6];
    const float* kn_w   = (const float*)d_in[7];
    const float* proj_w = (const float*)d_in[8];
    const float* proj_b = (const float*)d_in[9];
    float* outp = (float*)d_out;

    char* ws = (char*)d_ws;
    ushort* x_bf    = (ushort*)ws; ws += (size_t)TOK_X * CDIM * 2;
    ushort* y_bf    = (ushort*)ws; ws += (size_t)TOK_Y * CDIM * 2;
    ushort* qkvw_bf = (ushort*)ws; ws += (size_t)3 * CDIM * CDIM * 2;
    ushort* kvw_bf  = (ushort*)ws; ws += (size_t)2 * CDIM * CDIM * 2;
    ushort* projw_bf= (ushort*)ws; ws += (size_t)CDIM * CDIM * 2;
    ushort* qh      = (ushort*)ws; ws += (size_t)BHN * NTOK * 64 * 2;
    ushort* kc      = (ushort*)ws; ws += (size_t)BHN * SEQ * 64 * 2;
    ushort* vc      = (ushort*)ws; ws += (size_t)BHN * SEQ * 64 * 2;
    ushort* vt      = (ushort*)ws; ws += (size_t)BHN * SEQ * 64 * 2;
    ushort* ao      = (ushort*)ws; ws += (size_t)TOK_X * CDIM * 2;
    ushort* po      = (ushort*)ws; ws += (size_t)2 * TOK_X * CDIM * 2;   // 16 MB partial O
    float*  pl      = (float*)ws;  ws += (size_t)2 * BHN * NTOK * 4;     // 0.5 MB partial l

    int c0 = TOK_X * CDIM / 2048;
    int c1 = c0 + TOK_Y * CDIM / 2048;
    int c2 = c1 + 3 * CDIM * CDIM / 2048;
    int c3 = c2 + 2 * CDIM * CDIM / 2048;
    int c4 = c3 + CDIM * CDIM / 2048;
    cast_all<<<c4, 256, 0, stream>>>(x, x_bf, c0, y, y_bf, c1, qkv_w, qkvw_bf, c2,
                                     kv_w, kvw_bf, c3, proj_w, projw_bf);

    gemm_fused<1><<<dim3(3 * CDIM / 128, TOK_X / 128), 256, 0, stream>>>(
        x_bf, qkvw_bf, qkv_b, nullptr, qh, kc, vc, qn_w, kn_w, TOK_X, 3 * CDIM, CDIM);
    gemm_fused<2><<<dim3(2 * CDIM / 128, TOK_Y / 128), 256, 0, stream>>>(
        y_bf, kvw_bf, kv_b, nullptr, nullptr, kc, vc, qn_w, kn_w, TOK_Y, 2 * CDIM, CDIM);

    transpose_v<<<dim3(SEQ / 64, BHN), 256, 0, stream>>>(vc, vt);

    attn_fwd<<<dim3(NTOK / 128, BHN * 2), 256, 0, stream>>>(qh, kc, vt, po, pl);
    combine_halves<<<TOK_X * CDIM / 2048, 256, 0, stream>>>(po, pl, ao);

    gemm_fused<0><<<dim3(CDIM / 128, TOK_X / 128), 256, 0, stream>>>(
        ao, projw_bf, proj_b, outp, nullptr, nullptr, nullptr, nullptr, nullptr,
        TOK_X, CDIM, CDIM);
}

// Round 14
// 250.503 us; speedup vs baseline: 1.0442x; 1.0442x over previous
//
#include <hip/hip_runtime.h>

// ---------- constants for this problem ----------
#define BATCH 2
#define NTOK 2048          // image tokens per batch
#define MTOK 256           // text tokens per batch
#define CDIM 1024
#define NHEAD 16
#define HD 64
#define SEQ (NTOK + MTOK)  // 2304
#define TOK_X (BATCH * NTOK)   // 4096
#define TOK_Y (BATCH * MTOK)   // 512
#define BHN (BATCH * NHEAD)    // 32
#define NKT (SEQ / 64)         // 36 KV tiles

typedef __attribute__((ext_vector_type(8))) short bf16x8;
typedef __attribute__((ext_vector_type(4))) short bf16x4;
typedef __attribute__((ext_vector_type(4))) float f32x4;
typedef __attribute__((ext_vector_type(2))) unsigned int u32x2;
typedef __attribute__((ext_vector_type(4))) unsigned int u32x4;
#if __has_builtin(__builtin_amdgcn_cvt_pk_bf16_f32)
typedef __attribute__((ext_vector_type(2))) __bf16 bf16x2_t;
#endif

__device__ __forceinline__ float b2f(ushort u) {
    unsigned v = ((unsigned)u) << 16;
    return __builtin_bit_cast(float, v);
}
__device__ __forceinline__ ushort f2b(float f) {
    unsigned u = __builtin_bit_cast(unsigned, f);
    u += 0x7fffu + ((u >> 16) & 1u);   // round-to-nearest-even
    return (ushort)(u >> 16);
}
__device__ __forceinline__ unsigned pack2bf(float a, float b) {
#if __has_builtin(__builtin_amdgcn_cvt_pk_bf16_f32)
    bf16x2_t h = __builtin_amdgcn_cvt_pk_bf16_f32(a, b);   // lo=a, hi=b
    return __builtin_bit_cast(unsigned, h);
#else
    return ((unsigned)f2b(b) << 16) | (unsigned)f2b(a);
#endif
}

// async 16B global -> LDS; LDS dest = wave-uniform base, HW scatters lane*16B
__device__ __forceinline__ void async_load16(const ushort* g, ushort* l) {
    __builtin_amdgcn_global_load_lds(
        (const __attribute__((address_space(1))) unsigned*)(const void*)g,
        (__attribute__((address_space(3))) unsigned*)(void*)l, 16, 0, 0);
}

// ---------- one merged cast kernel: 5 fp32->bf16 segments ----------
__global__ __launch_bounds__(256) void cast_all(
    const float* __restrict__ s0, ushort* __restrict__ t0, int b0,
    const float* __restrict__ s1, ushort* __restrict__ t1, int b1,
    const float* __restrict__ s2, ushort* __restrict__ t2, int b2,
    const float* __restrict__ s3, ushort* __restrict__ t3, int b3,
    const float* __restrict__ s4, ushort* __restrict__ t4) {
    int blk = blockIdx.x;
    const float* s; ushort* t;
    if (blk < b0)      { s = s0; t = t0; }
    else if (blk < b1) { s = s1; t = t1; blk -= b0; }
    else if (blk < b2) { s = s2; t = t2; blk -= b1; }
    else if (blk < b3) { s = s3; t = t3; blk -= b2; }
    else               { s = s4; t = t4; blk -= b3; }
    int i = (blk * 256 + threadIdx.x) * 8;
    float4 a = *(const float4*)(s + i);
    float4 b = *(const float4*)(s + i + 4);
    ushort tmp[8] = {f2b(a.x), f2b(a.y), f2b(a.z), f2b(a.w),
                     f2b(b.x), f2b(b.y), f2b(b.z), f2b(b.w)};
    *(uint4*)(t + i) = *(const uint4*)tmp;
}

// ---------- fused GEMM: C = A * Bt^T + bias, with per-mode epilogue ----------
// R14: MODE 0/1 use a 1-D grid with XCD-aware decode (HW maps linear block id
// round-robin: xcd = blk & 7). Each XCD owns a contiguous 4-row M-strip x all
// N-cols, so co-resident blocks sharing A-tiles (same by) and B-tiles (same bx)
// live on the SAME XCD -> per-XCD L2 working set = small streaming window
// instead of the whole A matrix (8.8 MB > 4 MB L2 = thrash).
template <int MODE>
__global__ __launch_bounds__(256) void gemm_fused(const ushort* __restrict__ A,
                                                  const ushort* __restrict__ Bt,
                                                  const float* __restrict__ bias,
                                                  float* __restrict__ Cf,
                                                  ushort* __restrict__ d_q,
                                                  ushort* __restrict__ d_k,
                                                  ushort* __restrict__ d_v,
                                                  const float* __restrict__ qn_w,
                                                  const float* __restrict__ kn_w,
                                                  int M, int N, int K) {
    __shared__ ushort As[128][64];
    __shared__ ushort Bs[128][64];
    int tid = threadIdx.x;
    int lane = tid & 63;
    int w = tid >> 6;
    int wm = (w >> 1) * 64;
    int wn = (w & 1) * 64;
    int l15 = lane & 15;
    int quad = lane >> 4;
    int sw = l15 & 7;

    int bx, by;
    if (MODE == 2) {
        bx = blockIdx.x; by = blockIdx.y;
    } else {
        int xcd = blockIdx.x & 7;
        int loc = blockIdx.x >> 3;
        by = xcd * 4 + (loc & 3);   // each XCD: contiguous 4-row M strip
        bx = loc >> 2;              // all N columns
    }
    int bm = by * 128;
    int bn = bx * 128;

    f32x4 acc[4][4];
#pragma unroll
    for (int i = 0; i < 4; i++)
#pragma unroll
        for (int j = 0; j < 4; j++) acc[i][j] = (f32x4)0.0f;

    int lrow = lane >> 3;
    int lcol = ((lane & 7) ^ lrow) * 8;

    for (int k0 = 0; k0 < K; k0 += 64) {
        __syncthreads();
#pragma unroll
        for (int p = 0; p < 4; p++) {
            int rb = w * 32 + p * 8;
            async_load16(&A[(size_t)(bm + rb + lrow) * K + k0 + lcol], &As[rb][0]);
            async_load16(&Bt[(size_t)(bn + rb + lrow) * K + k0 + lcol], &Bs[rb][0]);
        }
        __syncthreads();
#pragma unroll
        for (int kk = 0; kk < 64; kk += 32) {
            bf16x8 af[4], bfr[4];
            int g = (kk >> 3) + quad;
            int csw = (g ^ sw) * 8;
#pragma unroll
            for (int i = 0; i < 4; i++)
                af[i] = *(const bf16x8*)&As[wm + i * 16 + l15][csw];
#pragma unroll
            for (int j = 0; j < 4; j++)
                bfr[j] = *(const bf16x8*)&Bs[wn + j * 16 + l15][csw];
#pragma unroll
            for (int i = 0; i < 4; i++)
#pragma unroll
                for (int j = 0; j < 4; j++)
                    acc[i][j] = __builtin_amdgcn_mfma_f32_16x16x32_bf16(af[i], bfr[j], acc[i][j], 0, 0, 0);
        }
    }

    int colbase = bn + wn;   // 64-aligned; one head's d-range
    float bv[4];
#pragma unroll
    for (int j = 0; j < 4; j++) bv[j] = bias[colbase + j * 16 + l15];
#pragma unroll
    for (int i = 0; i < 4; i++)
#pragma unroll
        for (int j = 0; j < 4; j++)
#pragma unroll
            for (int r = 0; r < 4; r++) acc[i][j][r] += bv[j];

    if (MODE == 0) {
#pragma unroll
        for (int i = 0; i < 4; i++) {
            int row0 = bm + wm + i * 16 + quad * 4;
#pragma unroll
            for (int j = 0; j < 4; j++) {
                int col = colbase + j * 16 + l15;
#pragma unroll
                for (int r = 0; r < 4; r++)
                    Cf[(size_t)(row0 + r) * N + col] = acc[i][j][r];
            }
        }
        return;
    }

    // MODE 1 (qkv): region 0=q,1=k,2=v ; MODE 2 (kv): region 0=k,1=v
    int region = colbase >> 10;
    int h = (colbase >> 6) & (NHEAD - 1);
    bool do_norm = (MODE == 1) ? (region <= 1) : (region == 0);
    if (do_norm) {
        const float* wv = (MODE == 1 && region == 0) ? qn_w : kn_w;
        float wj[4];
#pragma unroll
        for (int j = 0; j < 4; j++) wj[j] = wv[j * 16 + l15];
        float qs = (MODE == 1 && region == 0) ? (0.125f * 1.44269504088896f) : 1.0f;
#pragma unroll
        for (int i = 0; i < 4; i++)
#pragma unroll
            for (int r = 0; r < 4; r++) {
                float s = acc[i][0][r] * acc[i][0][r] + acc[i][1][r] * acc[i][1][r]
                        + acc[i][2][r] * acc[i][2][r] + acc[i][3][r] * acc[i][3][r];
                s += __shfl_xor(s, 1);
                s += __shfl_xor(s, 2);
                s += __shfl_xor(s, 4);
                s += __shfl_xor(s, 8);
                float rs = rsqrtf(s * (1.0f / 64.0f) + 1e-6f) * qs;
#pragma unroll
                for (int j = 0; j < 4; j++) acc[i][j][r] *= rs * wj[j];
            }
    }
#pragma unroll
    for (int i = 0; i < 4; i++) {
#pragma unroll
        for (int r = 0; r < 4; r++) {
            int t = bm + wm + i * 16 + quad * 4 + r;   // token row
            size_t base;
            ushort* dst;
            if (MODE == 1) {
                int b = t >> 11, n = t & (NTOK - 1);
                size_t bh = (size_t)(b * NHEAD + h);
                if (region == 0)      { dst = d_q; base = (bh * NTOK + n) * 64; }
                else if (region == 1) { dst = d_k; base = (bh * SEQ + n) * 64; }
                else                  { dst = d_v; base = (bh * SEQ + n) * 64; }
            } else {
                int b = t >> 8, m = t & (MTOK - 1);
                size_t bh = (size_t)(b * NHEAD + h);
                if (region == 0) { dst = d_k; base = (bh * SEQ + NTOK + m) * 64; }
                else             { dst = d_v; base = (bh * SEQ + NTOK + m) * 64; }
            }
#pragma unroll
            for (int j = 0; j < 4; j++)
                dst[base + j * 16 + l15] = f2b(acc[i][j][r]);
        }
    }
}

// ---------- transpose V: vc [BHN][SEQ][64] -> vt [BHN][64][SEQ] (k-PAIR-INTERLEAVED) ----------
__global__ __launch_bounds__(256) void transpose_v(const ushort* __restrict__ vc,
                                                   ushort* __restrict__ vt) {
    __shared__ ushort t[64][72];
    int bh = blockIdx.y;
    int s0 = blockIdx.x * 64;
    int tid = threadIdx.x;
    int r = tid >> 3, c = (tid & 7) * 8;
    const ushort* src = vc + ((size_t)bh * SEQ + s0) * 64;
    *(uint4*)&t[r][c] = *(const uint4*)&src[(size_t)r * 64 + c];
    *(uint4*)&t[r + 32][c] = *(const uint4*)&src[(size_t)(r + 32) * 64 + c];
    __syncthreads();
    ushort* dst = vt + (size_t)bh * 64 * SEQ + s0;
#pragma unroll
    for (int p = 0; p < 2; p++) {
        int d = (tid >> 3) + p * 32;
        int s8 = (tid & 7) * 8;
        ushort tmp[8];
#pragma unroll
        for (int i = 0; i < 8; i++) {
            int cc = s8 + i;                                // dst position
            int srcs = (cc & 32) + ((cc & 31) >> 1) + ((cc & 1) << 4);  // source key
            tmp[i] = t[srcs][d];
        }
        *(uint4*)&dst[(size_t)d * SEQ + s8] = *(const uint4*)tmp;
    }
}

// ---------- flash attention: 32 q/wave, 64-key dbuf tiles, x32 PV (R12) ----------
__global__ __launch_bounds__(256) void attn_fwd(const ushort* __restrict__ qh,
                                                const ushort* __restrict__ kc,
                                                const ushort* __restrict__ vt,
                                                ushort* __restrict__ out) {
    __shared__ ushort Ks[2][64][72];   // [buf][key][d]
    __shared__ ushort Vs[2][64][68];   // [buf][d][key-interleaved]
    int tid = threadIdx.x;
    int lane = tid & 63;
    int w = tid >> 6;
    int l15 = lane & 15;
    int quad = lane >> 4;
    int bh = blockIdx.y;
    int q0 = blockIdx.x * 128 + w * 32;

    const ushort* qpA = qh + ((size_t)bh * NTOK + q0 + l15) * 64 + quad * 8;
    const ushort* qpB = qpA + 16 * 64;
    bf16x8 qA0 = *(const bf16x8*)qpA;
    bf16x8 qA1 = *(const bf16x8*)(qpA + 32);
    bf16x8 qB0 = *(const bf16x8*)qpB;
    bf16x8 qB1 = *(const bf16x8*)(qpB + 32);

    float lA = 0.0f, lB = 0.0f;
    f32x4 OA[4], OB[4];
#pragma unroll
    for (int jd = 0; jd < 4; jd++) { OA[jd] = (f32x4)0.0f; OB[jd] = (f32x4)0.0f; }

    const ushort* kbase = kc + (size_t)bh * SEQ * 64;
    const ushort* vbase = vt + (size_t)bh * 64 * SEQ;
    int sr = tid >> 3, sc = (tid & 7) * 8;
    const ushort* kp0 = kbase + (size_t)sr * 64 + sc;
    const ushort* kp1 = kbase + (size_t)(sr + 32) * 64 + sc;
    const ushort* vp0 = vbase + (size_t)sr * SEQ + sc;
    const ushort* vp1 = vbase + (size_t)(sr + 32) * SEQ + sc;

    // prefetch tile 0 into registers
    uint4 rka = *(const uint4*)kp0;
    uint4 rkb = *(const uint4*)kp1;
    uint4 rva = *(const uint4*)vp0;
    uint4 rvb = *(const uint4*)vp1;

    for (int t = 0; t < NKT; t++) {
        int p = t & 1;
        *(uint4*)&Ks[p][sr][sc] = rka;
        *(uint4*)&Ks[p][sr + 32][sc] = rkb;
        *(uint4*)&Vs[p][sr][sc] = rva;
        *(uint4*)&Vs[p][sr + 32][sc] = rvb;
        __syncthreads();
        if (t + 1 < NKT) {
            int s0 = (t + 1) * 64;
            rka = *(const uint4*)(kp0 + (size_t)s0 * 64);
            rkb = *(const uint4*)(kp1 + (size_t)s0 * 64);
            rva = *(const uint4*)(vp0 + s0);
            rvb = *(const uint4*)(vp1 + s0);
        }

        f32x4 SA[4], SB[4];
#pragma unroll
        for (int j = 0; j < 4; j++) { SA[j] = (f32x4)0.0f; SB[j] = (f32x4)0.0f; }
#pragma unroll
        for (int j = 0; j < 4; j++) {
            bf16x8 kf = *(const bf16x8*)&Ks[p][j * 16 + l15][quad * 8];
            SA[j] = __builtin_amdgcn_mfma_f32_16x16x32_bf16(kf, qA0, SA[j], 0, 0, 0);
            SB[j] = __builtin_amdgcn_mfma_f32_16x16x32_bf16(kf, qB0, SB[j], 0, 0, 0);
        }
#pragma unroll
        for (int j = 0; j < 4; j++) {
            bf16x8 kf = *(const bf16x8*)&Ks[p][j * 16 + l15][32 + quad * 8];
            SA[j] = __builtin_amdgcn_mfma_f32_16x16x32_bf16(kf, qA1, SA[j], 0, 0, 0);
            SB[j] = __builtin_amdgcn_mfma_f32_16x16x32_bf16(kf, qB1, SB[j], 0, 0, 0);
        }

#pragma unroll
        for (int pb2 = 0; pb2 < 2; pb2++) {
            int j0 = 2 * pb2, j1 = j0 + 1;
            u32x4 wa, wb;
#pragma unroll
            for (int r = 0; r < 4; r++) {
                float a0 = __builtin_amdgcn_exp2f(SA[j0][r]);
                float a1 = __builtin_amdgcn_exp2f(SA[j1][r]);
                lA += a0 + a1;
                wa[r] = pack2bf(a0, a1);
                float b0 = __builtin_amdgcn_exp2f(SB[j0][r]);
                float b1 = __builtin_amdgcn_exp2f(SB[j1][r]);
                lB += b0 + b1;
                wb[r] = pack2bf(b0, b1);
            }
            bf16x8 pA = __builtin_bit_cast(bf16x8, wa);
            bf16x8 pB = __builtin_bit_cast(bf16x8, wb);
#pragma unroll
            for (int jd = 0; jd < 4; jd++) {
                bf16x8 vf = *(const bf16x8*)&Vs[p][jd * 16 + l15][pb2 * 32 + quad * 8];
                OA[jd] = __builtin_amdgcn_mfma_f32_16x16x32_bf16(vf, pA, OA[jd], 0, 0, 0);
                OB[jd] = __builtin_amdgcn_mfma_f32_16x16x32_bf16(vf, pB, OB[jd], 0, 0, 0);
            }
        }
    }
    lA += __shfl_xor(lA, 16);
    lA += __shfl_xor(lA, 32);
    lB += __shfl_xor(lB, 16);
    lB += __shfl_xor(lB, 32);
    float invA = 1.0f / lA;
    float invB = 1.0f / lB;
    int b = bh >> 4, h = bh & 15;
    int tokA = (b << 11) + q0 + l15;
    ushort* obaseA = out + ((size_t)tokA * NHEAD + h) * 64;
    ushort* obaseB = obaseA + (size_t)16 * NHEAD * 64;
#pragma unroll
    for (int jd = 0; jd < 4; jd++) {
        u32x2 pk;
        pk.x = pack2bf(OA[jd][0] * invA, OA[jd][1] * invA);
        pk.y = pack2bf(OA[jd][2] * invA, OA[jd][3] * invA);
        *(u32x2*)&obaseA[jd * 16 + quad * 4] = pk;
        pk.x = pack2bf(OB[jd][0] * invB, OB[jd][1] * invB);
        pk.y = pack2bf(OB[jd][2] * invB, OB[jd][3] * invB);
        *(u32x2*)&obaseB[jd * 16 + quad * 4] = pk;
    }
}

// ---------- launch ----------
extern "C" void kernel_launch(void* const* d_in, const int* in_sizes, int n_in,
                              void* d_out, int out_size, void* d_ws, size_t ws_size,
                              hipStream_t stream) {
    const float* x      = (const float*)d_in[0];
    const float* y      = (const float*)d_in[1];
    const float* qkv_w  = (const float*)d_in[2];
    const float* qkv_b  = (const float*)d_in[3];
    const float* kv_w   = (const float*)d_in[4];
    const float* kv_b   = (const float*)d_in[5];
    const float* qn_w   = (const float*)d_in[6];
    const float* kn_w   = (const float*)d_in[7];
    const float* proj_w = (const float*)d_in[8];
    const float* proj_b = (const float*)d_in[9];
    float* outp = (float*)d_out;

    char* ws = (char*)d_ws;
    ushort* x_bf    = (ushort*)ws; ws += (size_t)TOK_X * CDIM * 2;
    ushort* y_bf    = (ushort*)ws; ws += (size_t)TOK_Y * CDIM * 2;
    ushort* qkvw_bf = (ushort*)ws; ws += (size_t)3 * CDIM * CDIM * 2;
    ushort* kvw_bf  = (ushort*)ws; ws += (size_t)2 * CDIM * CDIM * 2;
    ushort* projw_bf= (ushort*)ws; ws += (size_t)CDIM * CDIM * 2;
    ushort* qh      = (ushort*)ws; ws += (size_t)BHN * NTOK * 64 * 2;
    ushort* kc      = (ushort*)ws; ws += (size_t)BHN * SEQ * 64 * 2;
    ushort* vc      = (ushort*)ws; ws += (size_t)BHN * SEQ * 64 * 2;
    ushort* vt      = (ushort*)ws; ws += (size_t)BHN * SEQ * 64 * 2;
    ushort* ao      = (ushort*)ws; ws += (size_t)TOK_X * CDIM * 2;

    int c0 = TOK_X * CDIM / 2048;
    int c1 = c0 + TOK_Y * CDIM / 2048;
    int c2 = c1 + 3 * CDIM * CDIM / 2048;
    int c3 = c2 + 2 * CDIM * CDIM / 2048;
    int c4 = c3 + CDIM * CDIM / 2048;
    cast_all<<<c4, 256, 0, stream>>>(x, x_bf, c0, y, y_bf, c1, qkv_w, qkvw_bf, c2,
                                     kv_w, kvw_bf, c3, proj_w, projw_bf);

    // qkv: 1-D grid 768, XCD-swizzled decode inside
    gemm_fused<1><<<768, 256, 0, stream>>>(
        x_bf, qkvw_bf, qkv_b, nullptr, qh, kc, vc, qn_w, kn_w, TOK_X, 3 * CDIM, CDIM);
    gemm_fused<2><<<dim3(2 * CDIM / 128, TOK_Y / 128), 256, 0, stream>>>(
        y_bf, kvw_bf, kv_b, nullptr, nullptr, kc, vc, qn_w, kn_w, TOK_Y, 2 * CDIM, CDIM);

    transpose_v<<<dim3(SEQ / 64, BHN), 256, 0, stream>>>(vc, vt);

    attn_fwd<<<dim3(NTOK / 128, BHN), 256, 0, stream>>>(qh, kc, vt, ao);

    // proj: 1-D grid 256, XCD-swizzled decode inside
    gemm_fused<0><<<256, 256, 0, stream>>>(
        ao, projw_bf, proj_b, outp, nullptr, nullptr, nullptr, nullptr, nullptr,
        TOK_X, CDIM, CDIM);
}

// Round 15
// 240.118 us; speedup vs baseline: 1.0894x; 1.0432x over previous
//
#include <hip/hip_runtime.h>

// ---------- constants for this problem ----------
#define BATCH 2
#define NTOK 2048          // image tokens per batch
#define MTOK 256           // text tokens per batch
#define CDIM 1024
#define NHEAD 16
#define HD 64
#define SEQ (NTOK + MTOK)  // 2304
#define TOK_X (BATCH * NTOK)   // 4096
#define TOK_Y (BATCH * MTOK)   // 512
#define BHN (BATCH * NHEAD)    // 32
#define NKT (SEQ / 64)         // 36 KV tiles
#define QKV_BLOCKS 768         // (3*CDIM/128) * (TOK_X/128) = 24*32
#define KV_BLOCKS 64           // (2*CDIM/128) * (TOK_Y/128) = 16*4

typedef __attribute__((ext_vector_type(8))) short bf16x8;
typedef __attribute__((ext_vector_type(4))) short bf16x4;
typedef __attribute__((ext_vector_type(4))) float f32x4;
typedef __attribute__((ext_vector_type(2))) unsigned int u32x2;
typedef __attribute__((ext_vector_type(4))) unsigned int u32x4;
#if __has_builtin(__builtin_amdgcn_cvt_pk_bf16_f32)
typedef __attribute__((ext_vector_type(2))) __bf16 bf16x2_t;
#endif

__device__ __forceinline__ float b2f(ushort u) {
    unsigned v = ((unsigned)u) << 16;
    return __builtin_bit_cast(float, v);
}
__device__ __forceinline__ ushort f2b(float f) {
    unsigned u = __builtin_bit_cast(unsigned, f);
    u += 0x7fffu + ((u >> 16) & 1u);   // round-to-nearest-even
    return (ushort)(u >> 16);
}
__device__ __forceinline__ unsigned pack2bf(float a, float b) {
#if __has_builtin(__builtin_amdgcn_cvt_pk_bf16_f32)
    bf16x2_t h = __builtin_amdgcn_cvt_pk_bf16_f32(a, b);   // lo=a, hi=b
    return __builtin_bit_cast(unsigned, h);
#else
    return ((unsigned)f2b(b) << 16) | (unsigned)f2b(a);
#endif
}

// async 16B global -> LDS; LDS dest = wave-uniform base, HW scatters lane*16B
__device__ __forceinline__ void async_load16(const ushort* g, ushort* l) {
    __builtin_amdgcn_global_load_lds(
        (const __attribute__((address_space(1))) unsigned*)(const void*)g,
        (__attribute__((address_space(3))) unsigned*)(void*)l, 16, 0, 0);
}

// ---------- one merged cast kernel: 5 fp32->bf16 segments ----------
__global__ __launch_bounds__(256) void cast_all(
    const float* __restrict__ s0, ushort* __restrict__ t0, int b0,
    const float* __restrict__ s1, ushort* __restrict__ t1, int b1,
    const float* __restrict__ s2, ushort* __restrict__ t2, int b2,
    const float* __restrict__ s3, ushort* __restrict__ t3, int b3,
    const float* __restrict__ s4, ushort* __restrict__ t4) {
    int blk = blockIdx.x;
    const float* s; ushort* t;
    if (blk < b0)      { s = s0; t = t0; }
    else if (blk < b1) { s = s1; t = t1; blk -= b0; }
    else if (blk < b2) { s = s2; t = t2; blk -= b1; }
    else if (blk < b3) { s = s3; t = t3; blk -= b2; }
    else               { s = s4; t = t4; blk -= b3; }
    int i = (blk * 256 + threadIdx.x) * 8;
    float4 a = *(const float4*)(s + i);
    float4 b = *(const float4*)(s + i + 4);
    ushort tmp[8] = {f2b(a.x), f2b(a.y), f2b(a.z), f2b(a.w),
                     f2b(b.x), f2b(b.y), f2b(b.z), f2b(b.w)};
    *(uint4*)(t + i) = *(const uint4*)tmp;
}

// ---------- merged qkv+kv GEMM, one launch (832 blocks) ----------
// blocks [0,768): qkv (XCD-swizzled decode), [768,832): kv. Epilogue does
// bias + rmsnorm(q,k) and scatters q->qh, k->kc, and V DIRECTLY into the
// pair-interleaved vt layout (key k -> pos 2*(k&15)+(k>>4) within its
// 32-block) -- kills the transpose kernel and the vc round-trip.
__global__ __launch_bounds__(256) void gemm_qkvkv(const ushort* __restrict__ Aq,
                                                  const ushort* __restrict__ Wq,
                                                  const float* __restrict__ bq,
                                                  const ushort* __restrict__ Ak,
                                                  const ushort* __restrict__ Wk,
                                                  const float* __restrict__ bk,
                                                  ushort* __restrict__ d_q,
                                                  ushort* __restrict__ d_k,
                                                  ushort* __restrict__ d_vt,
                                                  const float* __restrict__ qn_w,
                                                  const float* __restrict__ kn_w) {
    __shared__ ushort As[128][64];
    __shared__ ushort Bs[128][64];
    int tid = threadIdx.x;
    int lane = tid & 63;
    int w = tid >> 6;
    int wm = (w >> 1) * 64;
    int wn = (w & 1) * 64;
    int l15 = lane & 15;
    int quad = lane >> 4;
    int sw = l15 & 7;

    int blk = blockIdx.x;
    int mode, bx, by;
    const ushort *A, *Bt;
    const float* bias;
    if (blk < QKV_BLOCKS) {
        mode = 1;
        int xcd = blk & 7;
        int loc = blk >> 3;
        by = xcd * 4 + (loc & 3);   // each XCD: contiguous 4-row M strip
        bx = loc >> 2;
        A = Aq; Bt = Wq; bias = bq;
    } else {
        mode = 2;
        int loc = blk - QKV_BLOCKS;
        bx = loc & 15;
        by = loc >> 4;
        A = Ak; Bt = Wk; bias = bk;
    }
    int bm = by * 128;
    int bn = bx * 128;

    f32x4 acc[4][4];
#pragma unroll
    for (int i = 0; i < 4; i++)
#pragma unroll
        for (int j = 0; j < 4; j++) acc[i][j] = (f32x4)0.0f;

    int lrow = lane >> 3;
    int lcol = ((lane & 7) ^ lrow) * 8;

    for (int k0 = 0; k0 < CDIM; k0 += 64) {
        __syncthreads();
#pragma unroll
        for (int p = 0; p < 4; p++) {
            int rb = w * 32 + p * 8;
            async_load16(&A[(size_t)(bm + rb + lrow) * CDIM + k0 + lcol], &As[rb][0]);
            async_load16(&Bt[(size_t)(bn + rb + lrow) * CDIM + k0 + lcol], &Bs[rb][0]);
        }
        __syncthreads();
#pragma unroll
        for (int kk = 0; kk < 64; kk += 32) {
            bf16x8 af[4], bfr[4];
            int g = (kk >> 3) + quad;
            int csw = (g ^ sw) * 8;
#pragma unroll
            for (int i = 0; i < 4; i++)
                af[i] = *(const bf16x8*)&As[wm + i * 16 + l15][csw];
#pragma unroll
            for (int j = 0; j < 4; j++)
                bfr[j] = *(const bf16x8*)&Bs[wn + j * 16 + l15][csw];
#pragma unroll
            for (int i = 0; i < 4; i++)
#pragma unroll
                for (int j = 0; j < 4; j++)
                    acc[i][j] = __builtin_amdgcn_mfma_f32_16x16x32_bf16(af[i], bfr[j], acc[i][j], 0, 0, 0);
        }
    }

    int colbase = bn + wn;   // 64-aligned; one head's d-range
    float bv[4];
#pragma unroll
    for (int j = 0; j < 4; j++) bv[j] = bias[colbase + j * 16 + l15];
#pragma unroll
    for (int i = 0; i < 4; i++)
#pragma unroll
        for (int j = 0; j < 4; j++)
#pragma unroll
            for (int r = 0; r < 4; r++) acc[i][j][r] += bv[j];

    int region = colbase >> 10;
    int h = (colbase >> 6) & (NHEAD - 1);
    bool is_q = (mode == 1) && (region == 0);
    bool is_k = (mode == 1) ? (region == 1) : (region == 0);
    if (is_q || is_k) {
        const float* wv = is_q ? qn_w : kn_w;
        float wj[4];
#pragma unroll
        for (int j = 0; j < 4; j++) wj[j] = wv[j * 16 + l15];
        float qs = is_q ? (0.125f * 1.44269504088896f) : 1.0f;
#pragma unroll
        for (int i = 0; i < 4; i++)
#pragma unroll
            for (int r = 0; r < 4; r++) {
                float s = acc[i][0][r] * acc[i][0][r] + acc[i][1][r] * acc[i][1][r]
                        + acc[i][2][r] * acc[i][2][r] + acc[i][3][r] * acc[i][3][r];
                s += __shfl_xor(s, 1);
                s += __shfl_xor(s, 2);
                s += __shfl_xor(s, 4);
                s += __shfl_xor(s, 8);
                float rs = rsqrtf(s * (1.0f / 64.0f) + 1e-6f) * qs;
#pragma unroll
                for (int j = 0; j < 4; j++) acc[i][j][r] *= rs * wj[j];
            }
    }
    size_t l15seq = (size_t)l15 * SEQ;   // for v scatter
#pragma unroll
    for (int i = 0; i < 4; i++) {
#pragma unroll
        for (int r = 0; r < 4; r++) {
            int t = bm + wm + i * 16 + quad * 4 + r;   // token row
            int b, s;
            if (mode == 1) { b = t >> 11; s = t & (NTOK - 1); }
            else           { b = t >> 8;  s = NTOK + (t & (MTOK - 1)); }
            size_t bh = (size_t)(b * NHEAD + h);
            if (is_q) {
                size_t base = (bh * NTOK + s) * 64;
#pragma unroll
                for (int j = 0; j < 4; j++)
                    d_q[base + j * 16 + l15] = f2b(acc[i][j][r]);
            } else if (is_k) {
                size_t base = (bh * SEQ + s) * 64;
#pragma unroll
                for (int j = 0; j < 4; j++)
                    d_k[base + j * 16 + l15] = f2b(acc[i][j][r]);
            } else {
                // V -> vt [bh][d][pair-interleaved seq]: key s at pos
                // (s>>5)*32 + 2*(s&15) + ((s>>4)&1)
                int within = s & 31;
                int pos = ((s >> 5) << 5) + ((within & 15) << 1) + (within >> 4);
                size_t base = bh * 64 * SEQ + l15seq + pos;
#pragma unroll
                for (int j = 0; j < 4; j++)
                    d_vt[base + (size_t)(j * 16) * SEQ] = f2b(acc[i][j][r]);
            }
        }
    }
}

// ---------- proj GEMM: fp32 out + bias (XCD-swizzled 1-D grid 256) ----------
__global__ __launch_bounds__(256) void gemm_proj(const ushort* __restrict__ A,
                                                 const ushort* __restrict__ Bt,
                                                 const float* __restrict__ bias,
                                                 float* __restrict__ Cf) {
    __shared__ ushort As[128][64];
    __shared__ ushort Bs[128][64];
    int tid = threadIdx.x;
    int lane = tid & 63;
    int w = tid >> 6;
    int wm = (w >> 1) * 64;
    int wn = (w & 1) * 64;
    int l15 = lane & 15;
    int quad = lane >> 4;
    int sw = l15 & 7;
    int xcd = blockIdx.x & 7;
    int loc = blockIdx.x >> 3;
    int by = xcd * 4 + (loc & 3);
    int bx = loc >> 2;
    int bm = by * 128;
    int bn = bx * 128;

    f32x4 acc[4][4];
#pragma unroll
    for (int i = 0; i < 4; i++)
#pragma unroll
        for (int j = 0; j < 4; j++) acc[i][j] = (f32x4)0.0f;

    int lrow = lane >> 3;
    int lcol = ((lane & 7) ^ lrow) * 8;

    for (int k0 = 0; k0 < CDIM; k0 += 64) {
        __syncthreads();
#pragma unroll
        for (int p = 0; p < 4; p++) {
            int rb = w * 32 + p * 8;
            async_load16(&A[(size_t)(bm + rb + lrow) * CDIM + k0 + lcol], &As[rb][0]);
            async_load16(&Bt[(size_t)(bn + rb + lrow) * CDIM + k0 + lcol], &Bs[rb][0]);
        }
        __syncthreads();
#pragma unroll
        for (int kk = 0; kk < 64; kk += 32) {
            bf16x8 af[4], bfr[4];
            int g = (kk >> 3) + quad;
            int csw = (g ^ sw) * 8;
#pragma unroll
            for (int i = 0; i < 4; i++)
                af[i] = *(const bf16x8*)&As[wm + i * 16 + l15][csw];
#pragma unroll
            for (int j = 0; j < 4; j++)
                bfr[j] = *(const bf16x8*)&Bs[wn + j * 16 + l15][csw];
#pragma unroll
            for (int i = 0; i < 4; i++)
#pragma unroll
                for (int j = 0; j < 4; j++)
                    acc[i][j] = __builtin_amdgcn_mfma_f32_16x16x32_bf16(af[i], bfr[j], acc[i][j], 0, 0, 0);
        }
    }
#pragma unroll
    for (int i = 0; i < 4; i++) {
        int row0 = bm + wm + i * 16 + quad * 4;
#pragma unroll
        for (int j = 0; j < 4; j++) {
            int col = bn + wn + j * 16 + l15;
            float bvv = bias[col];
#pragma unroll
            for (int r = 0; r < 4; r++)
                Cf[(size_t)(row0 + r) * CDIM + col] = acc[i][j][r] + bvv;
        }
    }
}

// ---------- flash attention: 32 q/wave, 64-key dbuf tiles, x32 PV (R12/R14) ----------
__global__ __launch_bounds__(256) void attn_fwd(const ushort* __restrict__ qh,
                                                const ushort* __restrict__ kc,
                                                const ushort* __restrict__ vt,
                                                ushort* __restrict__ out) {
    __shared__ ushort Ks[2][64][72];   // [buf][key][d]
    __shared__ ushort Vs[2][64][68];   // [buf][d][key-interleaved]
    int tid = threadIdx.x;
    int lane = tid & 63;
    int w = tid >> 6;
    int l15 = lane & 15;
    int quad = lane >> 4;
    int bh = blockIdx.y;
    int q0 = blockIdx.x * 128 + w * 32;

    const ushort* qpA = qh + ((size_t)bh * NTOK + q0 + l15) * 64 + quad * 8;
    const ushort* qpB = qpA + 16 * 64;
    bf16x8 qA0 = *(const bf16x8*)qpA;
    bf16x8 qA1 = *(const bf16x8*)(qpA + 32);
    bf16x8 qB0 = *(const bf16x8*)qpB;
    bf16x8 qB1 = *(const bf16x8*)(qpB + 32);

    float lA = 0.0f, lB = 0.0f;
    f32x4 OA[4], OB[4];
#pragma unroll
    for (int jd = 0; jd < 4; jd++) { OA[jd] = (f32x4)0.0f; OB[jd] = (f32x4)0.0f; }

    int sr = tid >> 3, sc = (tid & 7) * 8;
    const ushort* kp0 = kc + (size_t)bh * SEQ * 64 + (size_t)sr * 64 + sc;
    const ushort* kp1 = kp0 + (size_t)32 * 64;
    const ushort* vp0 = vt + (size_t)bh * 64 * SEQ + (size_t)sr * SEQ + sc;
    const ushort* vp1 = vp0 + (size_t)32 * SEQ;

    // prefetch tile 0 into registers
    uint4 rka = *(const uint4*)kp0;
    uint4 rkb = *(const uint4*)kp1;
    uint4 rva = *(const uint4*)vp0;
    uint4 rvb = *(const uint4*)vp1;

    for (int t = 0; t < NKT; t++) {
        int p = t & 1;
        *(uint4*)&Ks[p][sr][sc] = rka;
        *(uint4*)&Ks[p][sr + 32][sc] = rkb;
        *(uint4*)&Vs[p][sr][sc] = rva;
        *(uint4*)&Vs[p][sr + 32][sc] = rvb;
        __syncthreads();
        if (t + 1 < NKT) {
            kp0 += 64 * 64; kp1 += 64 * 64; vp0 += 64; vp1 += 64;   // ptr increments
            rka = *(const uint4*)kp0;
            rkb = *(const uint4*)kp1;
            rva = *(const uint4*)vp0;
            rvb = *(const uint4*)vp1;
        }

        f32x4 SA[4], SB[4];
#pragma unroll
        for (int j = 0; j < 4; j++) { SA[j] = (f32x4)0.0f; SB[j] = (f32x4)0.0f; }
#pragma unroll
        for (int j = 0; j < 4; j++) {
            bf16x8 kf = *(const bf16x8*)&Ks[p][j * 16 + l15][quad * 8];
            SA[j] = __builtin_amdgcn_mfma_f32_16x16x32_bf16(kf, qA0, SA[j], 0, 0, 0);
            SB[j] = __builtin_amdgcn_mfma_f32_16x16x32_bf16(kf, qB0, SB[j], 0, 0, 0);
        }
#pragma unroll
        for (int j = 0; j < 4; j++) {
            bf16x8 kf = *(const bf16x8*)&Ks[p][j * 16 + l15][32 + quad * 8];
            SA[j] = __builtin_amdgcn_mfma_f32_16x16x32_bf16(kf, qA1, SA[j], 0, 0, 0);
            SB[j] = __builtin_amdgcn_mfma_f32_16x16x32_bf16(kf, qB1, SB[j], 0, 0, 0);
        }

#pragma unroll
        for (int pb2 = 0; pb2 < 2; pb2++) {
            int j0 = 2 * pb2, j1 = j0 + 1;
            u32x4 wa, wb;
#pragma unroll
            for (int r = 0; r < 4; r++) {
                float a0 = __builtin_amdgcn_exp2f(SA[j0][r]);
                float a1 = __builtin_amdgcn_exp2f(SA[j1][r]);
                lA += a0 + a1;
                wa[r] = pack2bf(a0, a1);
                float b0 = __builtin_amdgcn_exp2f(SB[j0][r]);
                float b1 = __builtin_amdgcn_exp2f(SB[j1][r]);
                lB += b0 + b1;
                wb[r] = pack2bf(b0, b1);
            }
            bf16x8 pA = __builtin_bit_cast(bf16x8, wa);
            bf16x8 pB = __builtin_bit_cast(bf16x8, wb);
#pragma unroll
            for (int jd = 0; jd < 4; jd++) {
                bf16x8 vf = *(const bf16x8*)&Vs[p][jd * 16 + l15][pb2 * 32 + quad * 8];
                OA[jd] = __builtin_amdgcn_mfma_f32_16x16x32_bf16(vf, pA, OA[jd], 0, 0, 0);
                OB[jd] = __builtin_amdgcn_mfma_f32_16x16x32_bf16(vf, pB, OB[jd], 0, 0, 0);
            }
        }
    }
    lA += __shfl_xor(lA, 16);
    lA += __shfl_xor(lA, 32);
    lB += __shfl_xor(lB, 16);
    lB += __shfl_xor(lB, 32);
    float invA = 1.0f / lA;
    float invB = 1.0f / lB;
    int b = bh >> 4, h = bh & 15;
    int tokA = (b << 11) + q0 + l15;
    ushort* obaseA = out + ((size_t)tokA * NHEAD + h) * 64;
    ushort* obaseB = obaseA + (size_t)16 * NHEAD * 64;
#pragma unroll
    for (int jd = 0; jd < 4; jd++) {
        u32x2 pk;
        pk.x = pack2bf(OA[jd][0] * invA, OA[jd][1] * invA);
        pk.y = pack2bf(OA[jd][2] * invA, OA[jd][3] * invA);
        *(u32x2*)&obaseA[jd * 16 + quad * 4] = pk;
        pk.x = pack2bf(OB[jd][0] * invB, OB[jd][1] * invB);
        pk.y = pack2bf(OB[jd][2] * invB, OB[jd][3] * invB);
        *(u32x2*)&obaseB[jd * 16 + quad * 4] = pk;
    }
}

// ---------- launch ----------
extern "C" void kernel_launch(void* const* d_in, const int* in_sizes, int n_in,
                              void* d_out, int out_size, void* d_ws, size_t ws_size,
                              hipStream_t stream) {
    const float* x      = (const float*)d_in[0];
    const float* y      = (const float*)d_in[1];
    const float* qkv_w  = (const float*)d_in[2];
    const float* qkv_b  = (const float*)d_in[3];
    const float* kv_w   = (const float*)d_in[4];
    const float* kv_b   = (const float*)d_in[5];
    const float* qn_w   = (const float*)d_in[6];
    const float* kn_w   = (const float*)d_in[7];
    const float* proj_w = (const float*)d_in[8];
    const float* proj_b = (const float*)d_in[9];
    float* outp = (float*)d_out;

    char* ws = (char*)d_ws;
    ushort* x_bf    = (ushort*)ws; ws += (size_t)TOK_X * CDIM * 2;
    ushort* y_bf    = (ushort*)ws; ws += (size_t)TOK_Y * CDIM * 2;
    ushort* qkvw_bf = (ushort*)ws; ws += (size_t)3 * CDIM * CDIM * 2;
    ushort* kvw_bf  = (ushort*)ws; ws += (size_t)2 * CDIM * CDIM * 2;
    ushort* projw_bf= (ushort*)ws; ws += (size_t)CDIM * CDIM * 2;
    ushort* qh      = (ushort*)ws; ws += (size_t)BHN * NTOK * 64 * 2;
    ushort* kc      = (ushort*)ws; ws += (size_t)BHN * SEQ * 64 * 2;
    ushort* vt      = (ushort*)ws; ws += (size_t)BHN * SEQ * 64 * 2;
    ushort* ao      = (ushort*)ws; ws += (size_t)TOK_X * CDIM * 2;

    int c0 = TOK_X * CDIM / 2048;
    int c1 = c0 + TOK_Y * CDIM / 2048;
    int c2 = c1 + 3 * CDIM * CDIM / 2048;
    int c3 = c2 + 2 * CDIM * CDIM / 2048;
    int c4 = c3 + CDIM * CDIM / 2048;
    cast_all<<<c4, 256, 0, stream>>>(x, x_bf, c0, y, y_bf, c1, qkv_w, qkvw_bf, c2,
                                     kv_w, kvw_bf, c3, proj_w, projw_bf);

    // qkv + kv projections in ONE launch; epilogue writes qh/kc and vt directly
    gemm_qkvkv<<<QKV_BLOCKS + KV_BLOCKS, 256, 0, stream>>>(
        x_bf, qkvw_bf, qkv_b, y_bf, kvw_bf, kv_b, qh, kc, vt, qn_w, kn_w);

    attn_fwd<<<dim3(NTOK / 128, BHN), 256, 0, stream>>>(qh, kc, vt, ao);

    gemm_proj<<<256, 256, 0, stream>>>(ao, projw_bf, proj_b, outp);
}

// Round 16
// 228.701 us; speedup vs baseline: 1.1437x; 1.0499x over previous
//
#include <hip/hip_runtime.h>

// ---------- constants for this problem ----------
#define BATCH 2
#define NTOK 2048          // image tokens per batch
#define MTOK 256           // text tokens per batch
#define CDIM 1024
#define NHEAD 16
#define HD 64
#define SEQ (NTOK + MTOK)  // 2304
#define TOK_X (BATCH * NTOK)   // 4096
#define TOK_Y (BATCH * MTOK)   // 512
#define BHN (BATCH * NHEAD)    // 32
#define NKT (SEQ / 64)         // 36 KV tiles
#define QKV_BLOCKS 1536        // (3*CDIM/64) * (TOK_X/128) = 48*32
#define KV_BLOCKS 128          // (2*CDIM/64) * (TOK_Y/128) = 32*4

typedef __attribute__((ext_vector_type(8))) short bf16x8;
typedef __attribute__((ext_vector_type(4))) short bf16x4;
typedef __attribute__((ext_vector_type(4))) float f32x4;
typedef __attribute__((ext_vector_type(2))) unsigned int u32x2;
typedef __attribute__((ext_vector_type(4))) unsigned int u32x4;
#if __has_builtin(__builtin_amdgcn_cvt_pk_bf16_f32)
typedef __attribute__((ext_vector_type(2))) __bf16 bf16x2_t;
#endif

__device__ __forceinline__ float b2f(ushort u) {
    unsigned v = ((unsigned)u) << 16;
    return __builtin_bit_cast(float, v);
}
__device__ __forceinline__ ushort f2b(float f) {
    unsigned u = __builtin_bit_cast(unsigned, f);
    u += 0x7fffu + ((u >> 16) & 1u);   // round-to-nearest-even
    return (ushort)(u >> 16);
}
__device__ __forceinline__ unsigned pack2bf(float a, float b) {
#if __has_builtin(__builtin_amdgcn_cvt_pk_bf16_f32)
    bf16x2_t h = __builtin_amdgcn_cvt_pk_bf16_f32(a, b);   // lo=a, hi=b
    return __builtin_bit_cast(unsigned, h);
#else
    return ((unsigned)f2b(b) << 16) | (unsigned)f2b(a);
#endif
}

// async 16B global -> LDS; LDS dest = wave-uniform base, HW scatters lane*16B
__device__ __forceinline__ void async_load16(const ushort* g, ushort* l) {
    __builtin_amdgcn_global_load_lds(
        (const __attribute__((address_space(1))) unsigned*)(const void*)g,
        (__attribute__((address_space(3))) unsigned*)(void*)l, 16, 0, 0);
}

// ---------- one merged cast kernel: 5 fp32->bf16 segments ----------
__global__ __launch_bounds__(256) void cast_all(
    const float* __restrict__ s0, ushort* __restrict__ t0, int b0,
    const float* __restrict__ s1, ushort* __restrict__ t1, int b1,
    const float* __restrict__ s2, ushort* __restrict__ t2, int b2,
    const float* __restrict__ s3, ushort* __restrict__ t3, int b3,
    const float* __restrict__ s4, ushort* __restrict__ t4) {
    int blk = blockIdx.x;
    const float* s; ushort* t;
    if (blk < b0)      { s = s0; t = t0; }
    else if (blk < b1) { s = s1; t = t1; blk -= b0; }
    else if (blk < b2) { s = s2; t = t2; blk -= b1; }
    else if (blk < b3) { s = s3; t = t3; blk -= b2; }
    else               { s = s4; t = t4; blk -= b3; }
    int i = (blk * 256 + threadIdx.x) * 8;
    float4 a = *(const float4*)(s + i);
    float4 b = *(const float4*)(s + i + 4);
    ushort tmp[8] = {f2b(a.x), f2b(a.y), f2b(a.z), f2b(a.w),
                     f2b(b.x), f2b(b.y), f2b(b.z), f2b(b.w)};
    *(uint4*)(t + i) = *(const uint4*)tmp;
}

// ---------- merged qkv+kv GEMM, 128x64 tiles, one launch (1664 blocks) ----------
// R16: tile 128(M)x64(N), 4 waves x (32x64), acc[2][4], LDS 24 KB -> 5-6
// blocks/CU co-resident (vs 2-3 at 128x128): the K-loop is latency-bound
// (load -> barrier -> compute, 16 iters), more co-resident blocks = overlap.
// One head per block (N-tile = 64 = one head's d range). Epilogue: bias +
// rmsnorm(q,k) + scatter q->qh, k->kc, V directly into pair-interleaved vt.
__global__ __launch_bounds__(256) void gemm_qkvkv(const ushort* __restrict__ Aq,
                                                  const ushort* __restrict__ Wq,
                                                  const float* __restrict__ bq,
                                                  const ushort* __restrict__ Ak,
                                                  const ushort* __restrict__ Wk,
                                                  const float* __restrict__ bk,
                                                  ushort* __restrict__ d_q,
                                                  ushort* __restrict__ d_k,
                                                  ushort* __restrict__ d_vt,
                                                  const float* __restrict__ qn_w,
                                                  const float* __restrict__ kn_w) {
    __shared__ ushort As[128][64];   // 16 KB
    __shared__ ushort Bs[64][64];    // 8 KB
    int tid = threadIdx.x;
    int lane = tid & 63;
    int w = tid >> 6;
    int wm = w * 32;
    int l15 = lane & 15;
    int quad = lane >> 4;
    int sw = l15 & 7;

    int blk = blockIdx.x;
    int mode, bx, by;
    const ushort *A, *Bt;
    const float* bias;
    if (blk < QKV_BLOCKS) {
        mode = 1;
        int xcd = blk & 7;
        int loc = blk >> 3;         // 0..191
        by = xcd * 4 + (loc & 3);   // 0..31: each XCD a contiguous 4-row M strip
        bx = loc >> 2;              // 0..47
        A = Aq; Bt = Wq; bias = bq;
    } else {
        mode = 2;
        int loc = blk - QKV_BLOCKS; // 0..127
        bx = loc & 31;              // 0..31
        by = loc >> 5;              // 0..3
        A = Ak; Bt = Wk; bias = bk;
    }
    int bm = by * 128;
    int bn = bx * 64;

    f32x4 acc[2][4];
#pragma unroll
    for (int i = 0; i < 2; i++)
#pragma unroll
        for (int j = 0; j < 4; j++) acc[i][j] = (f32x4)0.0f;

    int lrow = lane >> 3;
    int lcol = ((lane & 7) ^ lrow) * 8;

    for (int k0 = 0; k0 < CDIM; k0 += 64) {
        __syncthreads();
#pragma unroll
        for (int p = 0; p < 4; p++) {
            int rb = w * 32 + p * 8;
            async_load16(&A[(size_t)(bm + rb + lrow) * CDIM + k0 + lcol], &As[rb][0]);
        }
#pragma unroll
        for (int p = 0; p < 2; p++) {
            int rb = w * 16 + p * 8;
            async_load16(&Bt[(size_t)(bn + rb + lrow) * CDIM + k0 + lcol], &Bs[rb][0]);
        }
        __syncthreads();
#pragma unroll
        for (int kk = 0; kk < 64; kk += 32) {
            bf16x8 af[2], bfr[4];
            int g = (kk >> 3) + quad;
            int csw = (g ^ sw) * 8;
#pragma unroll
            for (int i = 0; i < 2; i++)
                af[i] = *(const bf16x8*)&As[wm + i * 16 + l15][csw];
#pragma unroll
            for (int j = 0; j < 4; j++)
                bfr[j] = *(const bf16x8*)&Bs[j * 16 + l15][csw];
#pragma unroll
            for (int i = 0; i < 2; i++)
#pragma unroll
                for (int j = 0; j < 4; j++)
                    acc[i][j] = __builtin_amdgcn_mfma_f32_16x16x32_bf16(af[i], bfr[j], acc[i][j], 0, 0, 0);
        }
    }

    float bv[4];
#pragma unroll
    for (int j = 0; j < 4; j++) bv[j] = bias[bn + j * 16 + l15];
#pragma unroll
    for (int i = 0; i < 2; i++)
#pragma unroll
        for (int j = 0; j < 4; j++)
#pragma unroll
            for (int r = 0; r < 4; r++) acc[i][j][r] += bv[j];

    int region = bn >> 10;
    int h = (bn >> 6) & (NHEAD - 1);
    bool is_q = (mode == 1) && (region == 0);
    bool is_k = (mode == 1) ? (region == 1) : (region == 0);
    if (is_q || is_k) {
        const float* wv = is_q ? qn_w : kn_w;
        float wj[4];
#pragma unroll
        for (int j = 0; j < 4; j++) wj[j] = wv[j * 16 + l15];
        float qs = is_q ? (0.125f * 1.44269504088896f) : 1.0f;
#pragma unroll
        for (int i = 0; i < 2; i++)
#pragma unroll
            for (int r = 0; r < 4; r++) {
                float s = acc[i][0][r] * acc[i][0][r] + acc[i][1][r] * acc[i][1][r]
                        + acc[i][2][r] * acc[i][2][r] + acc[i][3][r] * acc[i][3][r];
                s += __shfl_xor(s, 1);
                s += __shfl_xor(s, 2);
                s += __shfl_xor(s, 4);
                s += __shfl_xor(s, 8);
                float rs = rsqrtf(s * (1.0f / 64.0f) + 1e-6f) * qs;
#pragma unroll
                for (int j = 0; j < 4; j++) acc[i][j][r] *= rs * wj[j];
            }
    }
    size_t l15seq = (size_t)l15 * SEQ;   // for v scatter
#pragma unroll
    for (int i = 0; i < 2; i++) {
#pragma unroll
        for (int r = 0; r < 4; r++) {
            int t = bm + wm + i * 16 + quad * 4 + r;   // token row
            int b, s;
            if (mode == 1) { b = t >> 11; s = t & (NTOK - 1); }
            else           { b = t >> 8;  s = NTOK + (t & (MTOK - 1)); }
            size_t bh = (size_t)(b * NHEAD + h);
            if (is_q) {
                size_t base = (bh * NTOK + s) * 64;
#pragma unroll
                for (int j = 0; j < 4; j++)
                    d_q[base + j * 16 + l15] = f2b(acc[i][j][r]);
            } else if (is_k) {
                size_t base = (bh * SEQ + s) * 64;
#pragma unroll
                for (int j = 0; j < 4; j++)
                    d_k[base + j * 16 + l15] = f2b(acc[i][j][r]);
            } else {
                // V -> vt [bh][d][pair-interleaved seq]
                int within = s & 31;
                int pos = ((s >> 5) << 5) + ((within & 15) << 1) + (within >> 4);
                size_t base = bh * 64 * SEQ + l15seq + pos;
#pragma unroll
                for (int j = 0; j < 4; j++)
                    d_vt[base + (size_t)(j * 16) * SEQ] = f2b(acc[i][j][r]);
            }
        }
    }
}

// ---------- proj GEMM: 128x64 tiles, fp32 out + bias (XCD-swizzled grid 512) ----------
__global__ __launch_bounds__(256) void gemm_proj(const ushort* __restrict__ A,
                                                 const ushort* __restrict__ Bt,
                                                 const float* __restrict__ bias,
                                                 float* __restrict__ Cf) {
    __shared__ ushort As[128][64];
    __shared__ ushort Bs[64][64];
    int tid = threadIdx.x;
    int lane = tid & 63;
    int w = tid >> 6;
    int wm = w * 32;
    int l15 = lane & 15;
    int quad = lane >> 4;
    int sw = l15 & 7;
    int xcd = blockIdx.x & 7;
    int loc = blockIdx.x >> 3;      // 0..63
    int by = xcd * 4 + (loc & 3);   // 0..31
    int bx = loc >> 2;              // 0..15
    int bm = by * 128;
    int bn = bx * 64;

    f32x4 acc[2][4];
#pragma unroll
    for (int i = 0; i < 2; i++)
#pragma unroll
        for (int j = 0; j < 4; j++) acc[i][j] = (f32x4)0.0f;

    int lrow = lane >> 3;
    int lcol = ((lane & 7) ^ lrow) * 8;

    for (int k0 = 0; k0 < CDIM; k0 += 64) {
        __syncthreads();
#pragma unroll
        for (int p = 0; p < 4; p++) {
            int rb = w * 32 + p * 8;
            async_load16(&A[(size_t)(bm + rb + lrow) * CDIM + k0 + lcol], &As[rb][0]);
        }
#pragma unroll
        for (int p = 0; p < 2; p++) {
            int rb = w * 16 + p * 8;
            async_load16(&Bt[(size_t)(bn + rb + lrow) * CDIM + k0 + lcol], &Bs[rb][0]);
        }
        __syncthreads();
#pragma unroll
        for (int kk = 0; kk < 64; kk += 32) {
            bf16x8 af[2], bfr[4];
            int g = (kk >> 3) + quad;
            int csw = (g ^ sw) * 8;
#pragma unroll
            for (int i = 0; i < 2; i++)
                af[i] = *(const bf16x8*)&As[wm + i * 16 + l15][csw];
#pragma unroll
            for (int j = 0; j < 4; j++)
                bfr[j] = *(const bf16x8*)&Bs[j * 16 + l15][csw];
#pragma unroll
            for (int i = 0; i < 2; i++)
#pragma unroll
                for (int j = 0; j < 4; j++)
                    acc[i][j] = __builtin_amdgcn_mfma_f32_16x16x32_bf16(af[i], bfr[j], acc[i][j], 0, 0, 0);
        }
    }
#pragma unroll
    for (int i = 0; i < 2; i++) {
        int row0 = bm + wm + i * 16 + quad * 4;
#pragma unroll
        for (int j = 0; j < 4; j++) {
            int col = bn + j * 16 + l15;
            float bvv = bias[col];
#pragma unroll
            for (int r = 0; r < 4; r++)
                Cf[(size_t)(row0 + r) * CDIM + col] = acc[i][j][r] + bvv;
        }
    }
}

// ---------- flash attention: 32 q/wave, 64-key dbuf tiles, x32 PV (R15, unchanged) ----------
__global__ __launch_bounds__(256) void attn_fwd(const ushort* __restrict__ qh,
                                                const ushort* __restrict__ kc,
                                                const ushort* __restrict__ vt,
                                                ushort* __restrict__ out) {
    __shared__ ushort Ks[2][64][72];   // [buf][key][d]
    __shared__ ushort Vs[2][64][68];   // [buf][d][key-interleaved]
    int tid = threadIdx.x;
    int lane = tid & 63;
    int w = tid >> 6;
    int l15 = lane & 15;
    int quad = lane >> 4;
    int bh = blockIdx.y;
    int q0 = blockIdx.x * 128 + w * 32;

    const ushort* qpA = qh + ((size_t)bh * NTOK + q0 + l15) * 64 + quad * 8;
    const ushort* qpB = qpA + 16 * 64;
    bf16x8 qA0 = *(const bf16x8*)qpA;
    bf16x8 qA1 = *(const bf16x8*)(qpA + 32);
    bf16x8 qB0 = *(const bf16x8*)qpB;
    bf16x8 qB1 = *(const bf16x8*)(qpB + 32);

    float lA = 0.0f, lB = 0.0f;
    f32x4 OA[4], OB[4];
#pragma unroll
    for (int jd = 0; jd < 4; jd++) { OA[jd] = (f32x4)0.0f; OB[jd] = (f32x4)0.0f; }

    int sr = tid >> 3, sc = (tid & 7) * 8;
    const ushort* kp0 = kc + (size_t)bh * SEQ * 64 + (size_t)sr * 64 + sc;
    const ushort* kp1 = kp0 + (size_t)32 * 64;
    const ushort* vp0 = vt + (size_t)bh * 64 * SEQ + (size_t)sr * SEQ + sc;
    const ushort* vp1 = vp0 + (size_t)32 * SEQ;

    // prefetch tile 0 into registers
    uint4 rka = *(const uint4*)kp0;
    uint4 rkb = *(const uint4*)kp1;
    uint4 rva = *(const uint4*)vp0;
    uint4 rvb = *(const uint4*)vp1;

    for (int t = 0; t < NKT; t++) {
        int p = t & 1;
        *(uint4*)&Ks[p][sr][sc] = rka;
        *(uint4*)&Ks[p][sr + 32][sc] = rkb;
        *(uint4*)&Vs[p][sr][sc] = rva;
        *(uint4*)&Vs[p][sr + 32][sc] = rvb;
        __syncthreads();
        if (t + 1 < NKT) {
            kp0 += 64 * 64; kp1 += 64 * 64; vp0 += 64; vp1 += 64;   // ptr increments
            rka = *(const uint4*)kp0;
            rkb = *(const uint4*)kp1;
            rva = *(const uint4*)vp0;
            rvb = *(const uint4*)vp1;
        }

        f32x4 SA[4], SB[4];
#pragma unroll
        for (int j = 0; j < 4; j++) { SA[j] = (f32x4)0.0f; SB[j] = (f32x4)0.0f; }
#pragma unroll
        for (int j = 0; j < 4; j++) {
            bf16x8 kf = *(const bf16x8*)&Ks[p][j * 16 + l15][quad * 8];
            SA[j] = __builtin_amdgcn_mfma_f32_16x16x32_bf16(kf, qA0, SA[j], 0, 0, 0);
            SB[j] = __builtin_amdgcn_mfma_f32_16x16x32_bf16(kf, qB0, SB[j], 0, 0, 0);
        }
#pragma unroll
        for (int j = 0; j < 4; j++) {
            bf16x8 kf = *(const bf16x8*)&Ks[p][j * 16 + l15][32 + quad * 8];
            SA[j] = __builtin_amdgcn_mfma_f32_16x16x32_bf16(kf, qA1, SA[j], 0, 0, 0);
            SB[j] = __builtin_amdgcn_mfma_f32_16x16x32_bf16(kf, qB1, SB[j], 0, 0, 0);
        }

#pragma unroll
        for (int pb2 = 0; pb2 < 2; pb2++) {
            int j0 = 2 * pb2, j1 = j0 + 1;
            u32x4 wa, wb;
#pragma unroll
            for (int r = 0; r < 4; r++) {
                float a0 = __builtin_amdgcn_exp2f(SA[j0][r]);
                float a1 = __builtin_amdgcn_exp2f(SA[j1][r]);
                lA += a0 + a1;
                wa[r] = pack2bf(a0, a1);
                float b0 = __builtin_amdgcn_exp2f(SB[j0][r]);
                float b1 = __builtin_amdgcn_exp2f(SB[j1][r]);
                lB += b0 + b1;
                wb[r] = pack2bf(b0, b1);
            }
            bf16x8 pA = __builtin_bit_cast(bf16x8, wa);
            bf16x8 pB = __builtin_bit_cast(bf16x8, wb);
#pragma unroll
            for (int jd = 0; jd < 4; jd++) {
                bf16x8 vf = *(const bf16x8*)&Vs[p][jd * 16 + l15][pb2 * 32 + quad * 8];
                OA[jd] = __builtin_amdgcn_mfma_f32_16x16x32_bf16(vf, pA, OA[jd], 0, 0, 0);
                OB[jd] = __builtin_amdgcn_mfma_f32_16x16x32_bf16(vf, pB, OB[jd], 0, 0, 0);
            }
        }
    }
    lA += __shfl_xor(lA, 16);
    lA += __shfl_xor(lA, 32);
    lB += __shfl_xor(lB, 16);
    lB += __shfl_xor(lB, 32);
    float invA = 1.0f / lA;
    float invB = 1.0f / lB;
    int b = bh >> 4, h = bh & 15;
    int tokA = (b << 11) + q0 + l15;
    ushort* obaseA = out + ((size_t)tokA * NHEAD + h) * 64;
    ushort* obaseB = obaseA + (size_t)16 * NHEAD * 64;
#pragma unroll
    for (int jd = 0; jd < 4; jd++) {
        u32x2 pk;
        pk.x = pack2bf(OA[jd][0] * invA, OA[jd][1] * invA);
        pk.y = pack2bf(OA[jd][2] * invA, OA[jd][3] * invA);
        *(u32x2*)&obaseA[jd * 16 + quad * 4] = pk;
        pk.x = pack2bf(OB[jd][0] * invB, OB[jd][1] * invB);
        pk.y = pack2bf(OB[jd][2] * invB, OB[jd][3] * invB);
        *(u32x2*)&obaseB[jd * 16 + quad * 4] = pk;
    }
}

// ---------- launch ----------
extern "C" void kernel_launch(void* const* d_in, const int* in_sizes, int n_in,
                              void* d_out, int out_size, void* d_ws, size_t ws_size,
                              hipStream_t stream) {
    const float* x      = (const float*)d_in[0];
    const float* y      = (const float*)d_in[1];
    const float* qkv_w  = (const float*)d_in[2];
    const float* qkv_b  = (const float*)d_in[3];
    const float* kv_w   = (const float*)d_in[4];
    const float* kv_b   = (const float*)d_in[5];
    const float* qn_w   = (const float*)d_in[6];
    const float* kn_w   = (const float*)d_in[7];
    const float* proj_w = (const float*)d_in[8];
    const float* proj_b = (const float*)d_in[9];
    float* outp = (float*)d_out;

    char* ws = (char*)d_ws;
    ushort* x_bf    = (ushort*)ws; ws += (size_t)TOK_X * CDIM * 2;
    ushort* y_bf    = (ushort*)ws; ws += (size_t)TOK_Y * CDIM * 2;
    ushort* qkvw_bf = (ushort*)ws; ws += (size_t)3 * CDIM * CDIM * 2;
    ushort* kvw_bf  = (ushort*)ws; ws += (size_t)2 * CDIM * CDIM * 2;
    ushort* projw_bf= (ushort*)ws; ws += (size_t)CDIM * CDIM * 2;
    ushort* qh      = (ushort*)ws; ws += (size_t)BHN * NTOK * 64 * 2;
    ushort* kc      = (ushort*)ws; ws += (size_t)BHN * SEQ * 64 * 2;
    ushort* vt      = (ushort*)ws; ws += (size_t)BHN * SEQ * 64 * 2;
    ushort* ao      = (ushort*)ws; ws += (size_t)TOK_X * CDIM * 2;

    int c0 = TOK_X * CDIM / 2048;
    int c1 = c0 + TOK_Y * CDIM / 2048;
    int c2 = c1 + 3 * CDIM * CDIM / 2048;
    int c3 = c2 + 2 * CDIM * CDIM / 2048;
    int c4 = c3 + CDIM * CDIM / 2048;
    cast_all<<<c4, 256, 0, stream>>>(x, x_bf, c0, y, y_bf, c1, qkv_w, qkvw_bf, c2,
                                     kv_w, kvw_bf, c3, proj_w, projw_bf);

    gemm_qkvkv<<<QKV_BLOCKS + KV_BLOCKS, 256, 0, stream>>>(
        x_bf, qkvw_bf, qkv_b, y_bf, kvw_bf, kv_b, qh, kc, vt, qn_w, kn_w);

    attn_fwd<<<dim3(NTOK / 128, BHN), 256, 0, stream>>>(qh, kc, vt, ao);

    gemm_proj<<<512, 256, 0, stream>>>(ao, projw_bf, proj_b, outp);
}